// Round 11
// baseline (147.267 us; speedup 1.0000x reference)
//
#include <hip/hip_runtime.h>
#include <hip/hip_bf16.h>

// NCE / NT-Xent loss, B=4096, D=256, temp=0.5.
// loss = mean_i( log(sum_{j!=i} exp(sim_ij)) - sim_{i,(i+B)%N} ), N=8192.
// |sim| <= 1/temp = 2 => exp(sim) <= e^2: no online max needed, plain sum(exp).
//
// Zn stored scaled by sqrt(2*log2(e)) so MFMA output is the exp2 argument.
// Fragment-tiled Zn layout: 16-row group g is an 8KB contiguous block;
// lane l's fragment ks of group g = contiguous 16B at zn + g*4096 + ks*512 + l*8.
//
// R11: K-innermost canonical GEMM. R5-R10 plateau = compiler remat/spill of
// register-resident A saturating L1 (~8MB/CU reload traffic = 55us). New
// structure loads every fragment exactly once per use (remat-proof):
//   wave tile 64x64 (acc[4][4] = 64 VGPR, unrematerializable),
//   B panel 256x256 staged once to LDS (128KB, one barrier),
//   A streamed per-K-step from L2 (wave total 32KB = its minimum),
//   exp runs ONCE per output at the end (outside the MFMA loop).

constexpr int kN  = 8192;        // 2B rows
constexpr int kD  = 256;         // embedding dim
constexpr int kBH = 4096;        // B
constexpr int kRowsBlk = 128;    // rows per block (2 wave-rows x 64)
constexpr int kColsBlk = 256;    // cols per block (4 wave-cols x 64) -> 128KB LDS
constexpr float kSqrtScale = 1.6986436f;  // sqrt(2*log2(e))
constexpr float kLn2 = 0.6931471805599453f;

typedef __attribute__((ext_vector_type(8))) short bf16x8;  // 8 bf16 = 4 VGPRs
typedef __attribute__((ext_vector_type(4))) float f32x4;

__device__ __forceinline__ unsigned short f2bf(float f) {
  union { float f; unsigned u; } x;
  x.f = f;
  unsigned u = x.u;
  return (unsigned short)((u + 0x7FFFu + ((u >> 16) & 1u)) >> 16);
}

__device__ __forceinline__ void gload_lds16(const short* g, short* l) {
  __builtin_amdgcn_global_load_lds(
      (const __attribute__((address_space(1))) void*)g,
      (__attribute__((address_space(3))) void*)l, 16, 0, 0);
}

// ---------------- kernel 1: row-normalize fp32 -> bf16 (tiled + scaled) ---
__global__ void k_normalize(const float* __restrict__ e1,
                            const float* __restrict__ e2,
                            unsigned short* __restrict__ zn,
                            float* __restrict__ accum /* 2*kN floats */) {
  if (blockIdx.x < 16) {
    float4 z4 = {0.f, 0.f, 0.f, 0.f};
    *reinterpret_cast<float4*>(accum + blockIdx.x * 1024 + threadIdx.x * 4) = z4;
  }
  const int wave = threadIdx.x >> 6;
  const int lane = threadIdx.x & 63;
  const int row  = blockIdx.x * 4 + wave;
  const float* src = (row < kBH) ? (e1 + (size_t)row * kD)
                                 : (e2 + (size_t)(row - kBH) * kD);
  float4 v = *reinterpret_cast<const float4*>(src + lane * 4);
  float ssq = v.x * v.x + v.y * v.y + v.z * v.z + v.w * v.w;
#pragma unroll
  for (int m = 1; m < 64; m <<= 1) ssq += __shfl_xor(ssq, m);
  const float invs = kSqrtScale / sqrtf(ssq);   // eps can never bind (|z|~16)
  ushort4 o;
  o.x = f2bf(v.x * invs);
  o.y = f2bf(v.y * invs);
  o.z = f2bf(v.z * invs);
  o.w = f2bf(v.w * invs);
  // lane holds dims 4*lane..4*lane+3 -> ks=lane>>3, lhi=(lane>>1)&3, dlo=(lane&1)*4
  const int g  = row >> 4;
  const int rr = row & 15;
  const size_t dst = (size_t)g * 4096 + (lane >> 3) * 512 +
                     ((lane >> 1) & 3) * 128 + rr * 8 + (lane & 1) * 4;
  *reinterpret_cast<ushort4*>(zn + dst) = o;
}

// ---------------- kernel 2: fused Z.Z^T + per-row sum(exp) ----------------
// Grid: 64 row-tiles (128 rows) x 32 col-blocks (256 cols) = 2048 blocks.
// Block: 8 waves as 2x4; wave computes a 64x64 output tile with acc[4][4]
// (64 VGPR). K-innermost: per K-step load 4 A-frags (global, coalesced 1KB)
// + 4 B-frags (LDS) and do 16 MFMAs. exp/mask/fold epilogue runs once.
__global__ __launch_bounds__(512, 2)
void k_simlse(const unsigned short* __restrict__ zn,
              float* __restrict__ s_sum,
              float* __restrict__ pos_sum) {
  __shared__ __align__(16) short ldsB[16 * 4096];   // 128KB: 16 col-groups

  const int bid = blockIdx.x;
  const int rt  = bid >> 5;   // row tile 0..63 (128 rows)
  const int cb  = bid & 31;   // col block 0..31 (256 cols); fast -> L2 reuse of A
  const int tid = threadIdx.x;
  const int wave = tid >> 6;
  const int wr = wave >> 2;   // 0..1
  const int wc = wave & 3;    // 0..3
  const int lane = tid & 63;
  const int l15 = lane & 15;
  const int lhi = lane >> 4;

  const int rowBase  = rt * kRowsBlk + wr * 64;  // wave's first row
  const int colBase  = cb * kColsBlk;            // block's first col
  const int wcolBase = colBase + wc * 64;        // wave's first col

  // ---- stage B panel (16 groups = 128KB) once; linear dest ----
  {
    const short* src = (const short*)zn + (size_t)(cb * 16) * 4096;
#pragma unroll
    for (int r = 0; r < 16; ++r)
      gload_lds16(src + r * 4096 + tid * 8, &ldsB[r * 4096 + tid * 8]);
  }

  f32x4 acc[4][4];
#pragma unroll
  for (int g = 0; g < 4; ++g)
#pragma unroll
    for (int c = 0; c < 4; ++c) acc[g][c] = {0.f, 0.f, 0.f, 0.f};

  asm volatile("s_waitcnt vmcnt(0)" ::: "memory");
  __builtin_amdgcn_s_barrier();

  // ---- K-innermost MFMA loop: every fragment loaded once per use ----
  const unsigned short* aBase = zn + (size_t)(rowBase >> 4) * 4096 + lane * 8;
  const short* bBase = &ldsB[(wc * 4) * 4096 + lane * 8];

#pragma unroll
  for (int ks = 0; ks < 8; ++ks) {
    bf16x8 a[4], b[4];
#pragma unroll
    for (int g = 0; g < 4; ++g)
      a[g] = *reinterpret_cast<const bf16x8*>(aBase + g * 4096 + ks * 512);
#pragma unroll
    for (int c = 0; c < 4; ++c)
      b[c] = *reinterpret_cast<const bf16x8*>(bBase + c * 4096 + ks * 512);
#pragma unroll
    for (int g = 0; g < 4; ++g)
#pragma unroll
      for (int c = 0; c < 4; ++c)
        acc[g][c] = __builtin_amdgcn_mfma_f32_16x16x32_bf16(a[g], b[c], acc[g][c], 0, 0, 0);
  }

  // ---- epilogue: exp + diag/pos masking, once per output element ----
  float sacc[4][4];   // [g][j]
  float pacc[4][4];
#pragma unroll
  for (int g = 0; g < 4; ++g)
#pragma unroll
    for (int j = 0; j < 4; ++j) { sacc[g][j] = 0.f; pacc[g][j] = 0.f; }

#pragma unroll
  for (int g = 0; g < 4; ++g) {
    const int rbase16 = rowBase + g * 16;
    const int posc16  = (rbase16 + kBH) & (kN - 1);
#pragma unroll
    for (int c = 0; c < 4; ++c) {
      const int cb16 = wcolBase + c * 16;
      const bool diagT = (cb16 == rbase16);   // wave-uniform
      const bool posT  = (cb16 == posc16);    // wave-uniform
      const int ccol = cb16 + l15;            // C/D: col = lane&15
      if (!diagT && !posT) {
#pragma unroll
        for (int j = 0; j < 4; ++j)
          sacc[g][j] += exp2f(acc[g][c][j]);  // acc already = sim/temp*log2(e)
      } else {
#pragma unroll
        for (int j = 0; j < 4; ++j) {
          const int row = rbase16 + lhi * 4 + j;  // C/D: row=(lane>>4)*4+j
          float p = exp2f(acc[g][c][j]);
          if (diagT && ccol == row) p = 0.0f;                    // mask diag
          if (posT && ccol == ((row + kBH) & (kN - 1)))
            pacc[g][j] += acc[g][c][j] * kLn2;                   // sim/temp
          sacc[g][j] += p;
        }
      }
    }
  }

  // ---- fold across 16-lane column groups; l15==0 lanes own rows ----
#pragma unroll
  for (int g = 0; g < 4; ++g) {
    const int rbase16 = rowBase + g * 16;
    const int posc16  = (rbase16 + kBH) & (kN - 1);
    const bool hasPos = (posc16 >= wcolBase) && (posc16 < wcolBase + 64);
#pragma unroll
    for (int j = 0; j < 4; ++j) {
      float sv = sacc[g][j];
      float pv = pacc[g][j];
#pragma unroll
      for (int m = 1; m < 16; m <<= 1) {
        sv += __shfl_xor(sv, m);
        pv += __shfl_xor(pv, m);
      }
      if (l15 == 0) {
        const int row = rbase16 + lhi * 4 + j;
        atomicAdd(&s_sum[row], sv);
        if (hasPos) atomicAdd(&pos_sum[row], pv);
      }
    }
  }
}

// ---------------- kernel 3: log, subtract pos, final reduce ---------------
__global__ void k_final(const float* __restrict__ s_sum,
                        const float* __restrict__ pos_sum,
                        float* __restrict__ out) {
  __shared__ float red[16];
  float acc = 0.0f;
  for (int r = threadIdx.x; r < kN; r += 1024)
    acc += logf(s_sum[r]) - pos_sum[r];
#pragma unroll
  for (int m = 1; m < 64; m <<= 1) acc += __shfl_xor(acc, m);
  const int wave = threadIdx.x >> 6;
  const int lane = threadIdx.x & 63;
  if (lane == 0) red[wave] = acc;
  __syncthreads();
  if (threadIdx.x == 0) {
    float t = 0.0f;
#pragma unroll
    for (int w = 0; w < 16; ++w) t += red[w];
    out[0] = t / (float)kN;
  }
}

extern "C" void kernel_launch(void* const* d_in, const int* in_sizes, int n_in,
                              void* d_out, int out_size, void* d_ws, size_t ws_size,
                              hipStream_t stream) {
  const float* e1 = (const float*)d_in[0];
  const float* e2 = (const float*)d_in[1];
  float* out = (float*)d_out;

  // ws layout: [Zn bf16 tiled: N*D*2 = 4MB][s_sum: N*4][pos_sum: N*4] ~4.07MB
  unsigned short* zn = (unsigned short*)d_ws;
  float* s_sum   = (float*)((char*)d_ws + (size_t)kN * kD * 2);
  float* pos_sum = s_sum + kN;

  hipLaunchKernelGGL(k_normalize, dim3(kN / 4), dim3(256), 0, stream,
                     e1, e2, zn, s_sum);
  hipLaunchKernelGGL(k_simlse,
                     dim3((kN / kRowsBlk) * (kN / kColsBlk)), dim3(512), 0,
                     stream, zn, s_sum, pos_sum);
  hipLaunchKernelGGL(k_final, dim3(1), dim3(1024), 0, stream,
                     s_sum, pos_sum, out);
}

// Round 13
// 142.340 us; speedup vs baseline: 1.0346x; 1.0346x over previous
//
#include <hip/hip_runtime.h>
#include <hip/hip_bf16.h>

// NCE / NT-Xent loss, B=4096, D=256, temp=0.5.
// loss = mean_i( log(sum_{j!=i} exp(sim_ij)) - sim_{i,(i+B)%N} ), N=8192.
// |sim| <= 2 => exp(sim) <= e^2: no online max needed, plain sum(exp).
//
// Zn stored scaled by sqrt(2*log2(e)) so MFMA output IS the exp2 argument.
//
// R12: 32x32x16 MFMA + A-panel in LDS (reuse operand -> LDS, where the
// compiler CANNOT remat loads; R5-R11 showed register-resident A always
// degrades to an L1 reload storm). B streams from L2 exactly once per block.
//
// zn2 32-group fragment-tiled layout: for 32-row group g, the A/B fragment
// of K-step ks (16 k's) is the contiguous 1KB at shorts
//   zn2[g*8192 + ks*512 + lane*8]
// (lane&31 = row/col in group, lane>>5 = k-half, 8 bf16 per lane).
// A-operand and B-operand layouts coincide (row=lane&31 / col=lane&31),
// so one packing serves both sides of Z.Z^T.

constexpr int kN  = 8192;        // 2B rows
constexpr int kD  = 256;         // embedding dim
constexpr int kBH = 4096;        // B
constexpr int kRowsBlk = 128;    // rows per block (4 groups, 64KB LDS panel)
constexpr int kColsBlk = 256;    // cols per block
constexpr float kSqrtScale = 1.6986436f;  // sqrt(2*log2(e))
constexpr float kLn2 = 0.6931471805599453f;

typedef __attribute__((ext_vector_type(8))) short bf16x8;   // 4 VGPRs
typedef __attribute__((ext_vector_type(16))) float f32x16;  // 16 VGPRs

__device__ __forceinline__ unsigned short f2bf(float f) {
  union { float f; unsigned u; } x;
  x.f = f;
  unsigned u = x.u;
  return (unsigned short)((u + 0x7FFFu + ((u >> 16) & 1u)) >> 16);
}

__device__ __forceinline__ void gload_lds16(const short* g, short* l) {
  __builtin_amdgcn_global_load_lds(
      (const __attribute__((address_space(1))) void*)g,
      (__attribute__((address_space(3))) void*)l, 16, 0, 0);
}

// ---------------- kernel 1: row-normalize fp32 -> bf16 (32-group tiling) --
// One wave per row. Element (row, d): g=row>>5, r32=row&31, ks=d>>4,
// hi=(d>>3)&1, j=d&7 -> short idx g*8192 + ks*512 + (r32+hi*32)*8 + j.
// Writer lane holds d=4*lane..4*lane+3: ks=lane>>2, hi=(lane>>1)&1,
// j0=(lane&1)*4 -> one ushort4 store.
__global__ void k_normalize(const float* __restrict__ e1,
                            const float* __restrict__ e2,
                            unsigned short* __restrict__ zn2,
                            float* __restrict__ accum /* 2*kN floats */) {
  if (blockIdx.x < 16) {
    float4 z4 = {0.f, 0.f, 0.f, 0.f};
    *reinterpret_cast<float4*>(accum + blockIdx.x * 1024 + threadIdx.x * 4) = z4;
  }
  const int wave = threadIdx.x >> 6;
  const int lane = threadIdx.x & 63;
  const int row  = blockIdx.x * 4 + wave;
  const float* src = (row < kBH) ? (e1 + (size_t)row * kD)
                                 : (e2 + (size_t)(row - kBH) * kD);
  float4 v = *reinterpret_cast<const float4*>(src + lane * 4);
  float ssq = v.x * v.x + v.y * v.y + v.z * v.z + v.w * v.w;
#pragma unroll
  for (int m = 1; m < 64; m <<= 1) ssq += __shfl_xor(ssq, m);
  const float invs = kSqrtScale / sqrtf(ssq);   // eps can never bind (|z|~16)
  ushort4 o;
  o.x = f2bf(v.x * invs);
  o.y = f2bf(v.y * invs);
  o.z = f2bf(v.z * invs);
  o.w = f2bf(v.w * invs);
  const int g   = row >> 5;
  const int r32 = row & 31;
  const size_t dst = (size_t)g * 8192 + (lane >> 2) * 512 +
                     (r32 + ((lane >> 1) & 1) * 32) * 8 + (lane & 1) * 4;
  *reinterpret_cast<ushort4*>(zn2 + dst) = o;
}

// ---------------- kernel 2: fused Z.Z^T + per-row sum(exp) ----------------
// Grid: 64 row-tiles (128 rows) x 32 col-chunks (256 cols) = 2048 blocks.
// Block: 8 waves as 2(wr) x 4(wc); wave tile 64x64 = acc[2][2] f32x16.
// A panel (4 groups, 64KB) staged once to LDS; B streamed from L2 (each
// fragment loaded exactly once per use -> remat-proof by construction).
__global__ __launch_bounds__(512, 2)
void k_simlse(const unsigned short* __restrict__ zn2,
              float* __restrict__ s_sum,
              float* __restrict__ pos_sum) {
  __shared__ __align__(16) short ldsA[4 * 8192];   // 64KB: 4 row-groups

  const int bid = blockIdx.x;
  const int rt  = bid >> 5;   // row tile 0..63 (128 rows)
  const int ch  = bid & 31;   // col chunk 0..31 (256 cols); fast -> XCD spread
  const int tid = threadIdx.x;
  const int wave = tid >> 6;
  const int wr = wave >> 2;   // 0..1  (row half)
  const int wc = wave & 3;    // 0..3  (col quarter)
  const int lane = tid & 63;
  const int l31 = lane & 31;
  const int hi5 = lane >> 5;

  const int rowBase  = rt * kRowsBlk + wr * 64;   // wave's first row
  const int wcolBase = ch * kColsBlk + wc * 64;   // wave's first col

  // ---- stage A panel once: 64KB linear copy, 8 rounds x 512thr x 16B ----
  {
    const short* src = (const short*)zn2 + (size_t)(rt * 4) * 8192;
#pragma unroll
    for (int r = 0; r < 8; ++r)
      gload_lds16(src + r * 4096 + tid * 8, &ldsA[r * 4096 + tid * 8]);
  }

  f32x16 acc00 = {}, acc01 = {}, acc10 = {}, acc11 = {};

  asm volatile("s_waitcnt vmcnt(0)" ::: "memory");
  __builtin_amdgcn_s_barrier();

  // ---- K loop: 16 steps; per step 2 A ds_reads + 2 B global loads + 4 MFMA
  const short* aBase = &ldsA[(wr * 2) * 8192 + lane * 8];
  const unsigned short* bBase =
      zn2 + (size_t)(wcolBase >> 5) * 8192 + lane * 8;

#pragma unroll
  for (int ks = 0; ks < 16; ++ks) {
    bf16x8 a0 = *reinterpret_cast<const bf16x8*>(aBase + ks * 512);
    bf16x8 a1 = *reinterpret_cast<const bf16x8*>(aBase + 8192 + ks * 512);
    bf16x8 b0 = *reinterpret_cast<const bf16x8*>(bBase + ks * 512);
    bf16x8 b1 = *reinterpret_cast<const bf16x8*>(bBase + 8192 + ks * 512);
    acc00 = __builtin_amdgcn_mfma_f32_32x32x16_bf16(a0, b0, acc00, 0, 0, 0);
    acc01 = __builtin_amdgcn_mfma_f32_32x32x16_bf16(a0, b1, acc01, 0, 0, 0);
    acc10 = __builtin_amdgcn_mfma_f32_32x32x16_bf16(a1, b0, acc10, 0, 0, 0);
    acc11 = __builtin_amdgcn_mfma_f32_32x32x16_bf16(a1, b1, acc11, 0, 0, 0);
  }

  // ---- epilogue: exp + diag mask + pos extract + row-sum fold ----------
  // C/D layout (32x32): col = lane&31, row = (reg&3)+8*(reg>>2)+4*(lane>>5).
  float sacc[2][16];
#pragma unroll
  for (int g = 0; g < 2; ++g)
#pragma unroll
    for (int r = 0; r < 16; ++r) sacc[g][r] = 0.f;

#pragma unroll
  for (int g = 0; g < 2; ++g) {
    const int rbase32 = rowBase + g * 32;
    const int posc32  = (rbase32 + kBH) & (kN - 1);
#pragma unroll
    for (int c = 0; c < 2; ++c) {
      const f32x16 acc = (g == 0) ? (c == 0 ? acc00 : acc01)
                                  : (c == 0 ? acc10 : acc11);
      const int cb32 = wcolBase + c * 32;
      const bool diagT = (cb32 == rbase32);   // wave-uniform
      const bool posT  = (cb32 == posc32);    // wave-uniform
      if (!diagT && !posT) {
#pragma unroll
        for (int r = 0; r < 16; ++r)
          sacc[g][r] += exp2f(acc[r]);        // acc = sim/temp*log2(e)
      } else {
        const int col = cb32 + l31;
#pragma unroll
        for (int r = 0; r < 16; ++r) {
          const int row = rbase32 + (r & 3) + 8 * (r >> 2) + 4 * hi5;
          float p = exp2f(acc[r]);
          if (diagT && col == row) p = 0.0f;
          if (posT && col == ((row + kBH) & (kN - 1)))
            atomicAdd(&pos_sum[row], acc[r] * kLn2);   // ~2 lanes/reg, rare
          sacc[g][r] += p;
        }
      }
    }
  }

  // fold across the 32 lanes of each row (masks 1..16 stay in 32-lane half)
#pragma unroll
  for (int g = 0; g < 2; ++g) {
    const int rbase32 = rowBase + g * 32;
#pragma unroll
    for (int r = 0; r < 16; ++r) {
      float sv = sacc[g][r];
#pragma unroll
      for (int m = 1; m < 32; m <<= 1) sv += __shfl_xor(sv, m);
      if (l31 == 0) {
        const int row = rbase32 + (r & 3) + 8 * (r >> 2) + 4 * hi5;
        atomicAdd(&s_sum[row], sv);
      }
    }
  }
}

// ---------------- kernel 3: log, subtract pos, final reduce ---------------
__global__ void k_final(const float* __restrict__ s_sum,
                        const float* __restrict__ pos_sum,
                        float* __restrict__ out) {
  __shared__ float red[16];
  float acc = 0.0f;
  for (int r = threadIdx.x; r < kN; r += 1024)
    acc += logf(s_sum[r]) - pos_sum[r];
#pragma unroll
  for (int m = 1; m < 64; m <<= 1) acc += __shfl_xor(acc, m);
  const int wave = threadIdx.x >> 6;
  const int lane = threadIdx.x & 63;
  if (lane == 0) red[wave] = acc;
  __syncthreads();
  if (threadIdx.x == 0) {
    float t = 0.0f;
#pragma unroll
    for (int w = 0; w < 16; ++w) t += red[w];
    out[0] = t / (float)kN;
  }
}

extern "C" void kernel_launch(void* const* d_in, const int* in_sizes, int n_in,
                              void* d_out, int out_size, void* d_ws, size_t ws_size,
                              hipStream_t stream) {
  const float* e1 = (const float*)d_in[0];
  const float* e2 = (const float*)d_in[1];
  float* out = (float*)d_out;

  // ws layout: [Zn2 bf16 tiled: N*D*2 = 4MB][s_sum: N*4][pos_sum: N*4]
  unsigned short* zn2 = (unsigned short*)d_ws;
  float* s_sum   = (float*)((char*)d_ws + (size_t)kN * kD * 2);
  float* pos_sum = s_sum + kN;

  hipLaunchKernelGGL(k_normalize, dim3(kN / 4), dim3(256), 0, stream,
                     e1, e2, zn2, s_sum);
  hipLaunchKernelGGL(k_simlse,
                     dim3((kN / kRowsBlk) * (kN / kColsBlk)), dim3(512), 0,
                     stream, zn2, s_sum, pos_sum);
  hipLaunchKernelGGL(k_final, dim3(1), dim3(1024), 0, stream,
                     s_sum, pos_sum, out);
}

// Round 14
// 63.739 us; speedup vs baseline: 2.3105x; 2.2332x over previous
//
#include <hip/hip_runtime.h>
#include <hip/hip_bf16.h>

// NCE / NT-Xent loss, B=4096, D=256, temp=0.5.
// loss = mean_i( log(sum_{j!=i} exp(sim_ij)) - sim_{i,(i+B)%N} ), N=8192.
// |sim| <= 2 => exp(sim) <= e^2: plain sum(exp), no online max.
//
// R14 (base = R7, the 55.5us best):
//  * Hot loop is now a PURE unmasked GEMM+exp+rowsum. Algebraic offload:
//      - diag: row sums keep exp(s_ii); k_final subtracts exp2(||zhat_i||^2
//        scaled), recomputed bit-near-identically from the same bf16 data.
//      - pos:  pos_i = zhat_i . zhat_{i+B} computed by a tiny k_pos kernel
//        (4096 row-pair dots), not extracted from the GEMM.
//    -> epilogue = exactly 8 exp2 + 8 add per tile, branch-free.
//  * 3-stage software pipeline with static ping-pong regs:
//      load(t+1) -> MFMA(t) -> epi(t-1): the exp chain covers L2 latency.
//
// Zn stored scaled by sqrt(2*log2(e)) so MFMA output IS the exp2 argument.
// Fragment-tiled Zn: 16-row group g, element (g*16+rr, d), ks=d>>5,
// lhi=(d>>3)&3, dlo=d&7 -> zn[g*4096 + ks*512 + lhi*128 + rr*8 + dlo];
// lane l's fragment ks of group g = 16B at zn + g*4096 + ks*512 + l*8.

constexpr int kN  = 8192;        // 2B rows
constexpr int kD  = 256;         // embedding dim
constexpr int kBH = 4096;        // B
constexpr int kChunks  = 32;     // column chunks (256 cols each)
constexpr int kColsPer = kN / kChunks;
constexpr float kSqrtScale = 1.6986436f;  // sqrt(2*log2(e))
constexpr float kLn2 = 0.6931471805599453f;

typedef __attribute__((ext_vector_type(8))) short bf16x8;  // 4 VGPRs
typedef __attribute__((ext_vector_type(4))) float f32x4;

__device__ __forceinline__ unsigned short f2bf(float f) {
  union { float f; unsigned u; } x;
  x.f = f;
  unsigned u = x.u;
  return (unsigned short)((u + 0x7FFFu + ((u >> 16) & 1u)) >> 16);
}
__device__ __forceinline__ float bf2f(unsigned short h) {
  union { unsigned u; float f; } x;
  x.u = ((unsigned)h) << 16;
  return x.f;
}

// ---------------- kernel 1: row-normalize fp32 -> bf16 (tiled + scaled) ---
// Blocks 0..7 zero s_sum (8192 floats); stream order guarantees completion
// before k_simlse's atomicAdds.
__global__ void k_normalize(const float* __restrict__ e1,
                            const float* __restrict__ e2,
                            unsigned short* __restrict__ zn,
                            float* __restrict__ s_sum) {
  if (blockIdx.x < 8) {
    float4 z4 = {0.f, 0.f, 0.f, 0.f};
    *reinterpret_cast<float4*>(s_sum + blockIdx.x * 1024 + threadIdx.x * 4) = z4;
  }
  const int wave = threadIdx.x >> 6;
  const int lane = threadIdx.x & 63;
  const int row  = blockIdx.x * 4 + wave;
  const float* src = (row < kBH) ? (e1 + (size_t)row * kD)
                                 : (e2 + (size_t)(row - kBH) * kD);
  float4 v = *reinterpret_cast<const float4*>(src + lane * 4);
  float ssq = v.x * v.x + v.y * v.y + v.z * v.z + v.w * v.w;
#pragma unroll
  for (int m = 1; m < 64; m <<= 1) ssq += __shfl_xor(ssq, m);
  const float invs = kSqrtScale / sqrtf(ssq);   // eps can never bind (|z|~16)
  ushort4 o;
  o.x = f2bf(v.x * invs);
  o.y = f2bf(v.y * invs);
  o.z = f2bf(v.z * invs);
  o.w = f2bf(v.w * invs);
  const int g  = row >> 4;
  const int rr = row & 15;
  const size_t dst = (size_t)g * 4096 + (lane >> 3) * 512 +
                     ((lane >> 1) & 3) * 128 + rr * 8 + (lane & 1) * 4;
  *reinterpret_cast<ushort4*>(zn + dst) = o;
}

// ---------------- kernel 1b: row-pair dots (pos + diag), 1 wave/pair ------
// pair p: rows i=p, j=p+B. pos_val[i]=pos_val[j]=(zh_i.zh_j)*ln2 (=sim/temp);
// dacc[i]=||zh_i||^2 (scaled units, = MFMA's diag acc up to summation order).
__global__ void k_pos(const unsigned short* __restrict__ zn,
                      float* __restrict__ pos_val,
                      float* __restrict__ dacc) {
  const int wave = threadIdx.x >> 6;
  const int lane = threadIdx.x & 63;
  const int i = blockIdx.x * 4 + wave;        // 0..4095
  const int j = i + kBH;
  const int rr = i & 15;
  const size_t off = (size_t)(i >> 4) * 4096 + (lane >> 3) * 512 +
                     ((lane >> 1) & 3) * 128 + rr * 8 + (lane & 1) * 4;
  ushort4 ua = *reinterpret_cast<const ushort4*>(zn + off);
  ushort4 ub = *reinterpret_cast<const ushort4*>(zn + off + (size_t)256 * 4096);
  float dij = 0.f, dii = 0.f, djj = 0.f;
  const unsigned short* pa = &ua.x;
  const unsigned short* pb = &ub.x;
#pragma unroll
  for (int q = 0; q < 4; ++q) {
    const float a = bf2f(pa[q]);
    const float b = bf2f(pb[q]);
    dij += a * b;
    dii += a * a;
    djj += b * b;
  }
#pragma unroll
  for (int m = 1; m < 64; m <<= 1) {
    dij += __shfl_xor(dij, m);
    dii += __shfl_xor(dii, m);
    djj += __shfl_xor(djj, m);
  }
  if (lane == 0) {
    const float p = dij * kLn2;   // scaled-dot * ln2 == sim/temp
    pos_val[i] = p;
    pos_val[j] = p;
    dacc[i] = dii;
    dacc[j] = djj;
  }
}

// ---------------- kernel 2: pure GEMM + exp + row-sum ---------------------
// Grid: 64 row-tiles (128 rows) x 32 col-chunks (256 cols) = 2048 blocks.
// Block: 4 waves; wave = 32 rows (two 16-row subtiles). 3-stage pipeline:
// per steady iter: load(t+1) | MFMA(t) | epi(t-1). Branch-free epilogue.
__global__ __launch_bounds__(256, 3)
void k_simlse(const unsigned short* __restrict__ zn,
              float* __restrict__ s_sum) {
  const int bid = blockIdx.x;
  const int rt  = bid >> 5;   // row tile 0..63
  const int ch  = bid & 31;   // column chunk 0..31 (fast -> XCD L2 spread)
  const int wave = threadIdx.x >> 6;
  const int lane = threadIdx.x & 63;
  const int l15 = lane & 15;
  const int lhi = lane >> 4;
  const int rowBase = rt * 128 + wave * 32;
  const int colBase = ch * kColsPer;

  // A fragments (2 groups = 32 rows) from tiled layout.
  bf16x8 a0[8], a1[8];
  {
    const unsigned short* ap = zn + (size_t)(rowBase >> 4) * 4096 + lane * 8;
#pragma unroll
    for (int ks = 0; ks < 8; ++ks) {
      a0[ks] = *reinterpret_cast<const bf16x8*>(ap + ks * 512);
      a1[ks] = *reinterpret_cast<const bf16x8*>(ap + 4096 + ks * 512);
    }
  }

  float sacc[2][4] = {{0.f,0.f,0.f,0.f},{0.f,0.f,0.f,0.f}};

  bf16x8 bA[8], bB[8];
  f32x4 accA0, accA1, accB0, accB1;

  const unsigned short* bRoot = zn + lane * 8;

  auto loadA_ = [&](int tile) {   // into bA
    const unsigned short* bp = bRoot + (size_t)((colBase >> 4) + tile) * 4096;
#pragma unroll
    for (int ks = 0; ks < 8; ++ks)
      bA[ks] = *reinterpret_cast<const bf16x8*>(bp + ks * 512);
  };
  auto loadB_ = [&](int tile) {   // into bB
    const unsigned short* bp = bRoot + (size_t)((colBase >> 4) + tile) * 4096;
#pragma unroll
    for (int ks = 0; ks < 8; ++ks)
      bB[ks] = *reinterpret_cast<const bf16x8*>(bp + ks * 512);
  };
  auto mfmaA = [&]() {            // bA -> accA*
    accA0 = {0.f,0.f,0.f,0.f};
    accA1 = {0.f,0.f,0.f,0.f};
#pragma unroll
    for (int ks = 0; ks < 8; ++ks) {
      accA0 = __builtin_amdgcn_mfma_f32_16x16x32_bf16(a0[ks], bA[ks], accA0, 0, 0, 0);
      accA1 = __builtin_amdgcn_mfma_f32_16x16x32_bf16(a1[ks], bA[ks], accA1, 0, 0, 0);
    }
  };
  auto mfmaB = [&]() {            // bB -> accB*
    accB0 = {0.f,0.f,0.f,0.f};
    accB1 = {0.f,0.f,0.f,0.f};
#pragma unroll
    for (int ks = 0; ks < 8; ++ks) {
      accB0 = __builtin_amdgcn_mfma_f32_16x16x32_bf16(a0[ks], bB[ks], accB0, 0, 0, 0);
      accB1 = __builtin_amdgcn_mfma_f32_16x16x32_bf16(a1[ks], bB[ks], accB1, 0, 0, 0);
    }
  };
  auto epiA = [&]() {             // consume accA*: 8 exp2 + 8 add, no branches
#pragma unroll
    for (int j = 0; j < 4; ++j) {
      sacc[0][j] += exp2f(accA0[j]);
      sacc[1][j] += exp2f(accA1[j]);
    }
  };
  auto epiB = [&]() {
#pragma unroll
    for (int j = 0; j < 4; ++j) {
      sacc[0][j] += exp2f(accB0[j]);
      sacc[1][j] += exp2f(accB1[j]);
    }
  };

  // ---- pipeline: 16 tiles. prologue t0; steady pairs (1,2)..(13,14); tail 15.
  loadA_(0);
  loadB_(1);
  mfmaA();                 // tile 0
#pragma unroll 1
  for (int t = 1; t <= 13; t += 2) {
    loadA_(t + 1);         // overwrite bA (consumed)
    mfmaB();               // tile t
    epiA();                // tile t-1 (covers loadA_ latency)
    loadB_(t + 2);         // prefetch odd tile
    mfmaA();               // tile t+1
    epiB();                // tile t
  }
  mfmaB();                 // tile 15
  epiA();                  // tile 14
  epiB();                  // tile 15

  // ---- fold across the 16-lane column group; l15==0 lanes own rows ----
#pragma unroll
  for (int s = 0; s < 2; ++s) {
#pragma unroll
    for (int j = 0; j < 4; ++j) {
      float sv = sacc[s][j];
#pragma unroll
      for (int m = 1; m < 16; m <<= 1) sv += __shfl_xor(sv, m);
      if (l15 == 0) {
        const int row = rowBase + s * 16 + lhi * 4 + j;
        atomicAdd(&s_sum[row], sv);
      }
    }
  }
}

// ---------------- kernel 3: log(S - diag) - pos, final reduce -------------
__global__ void k_final(const float* __restrict__ s_sum,
                        const float* __restrict__ dacc,
                        const float* __restrict__ pos_val,
                        float* __restrict__ out) {
  __shared__ float red[16];
  float acc = 0.0f;
  for (int r = threadIdx.x; r < kN; r += 1024)
    acc += logf(s_sum[r] - exp2f(dacc[r])) - pos_val[r];
#pragma unroll
  for (int m = 1; m < 64; m <<= 1) acc += __shfl_xor(acc, m);
  const int wave = threadIdx.x >> 6;
  const int lane = threadIdx.x & 63;
  if (lane == 0) red[wave] = acc;
  __syncthreads();
  if (threadIdx.x == 0) {
    float t = 0.0f;
#pragma unroll
    for (int w = 0; w < 16; ++w) t += red[w];
    out[0] = t / (float)kN;
  }
}

extern "C" void kernel_launch(void* const* d_in, const int* in_sizes, int n_in,
                              void* d_out, int out_size, void* d_ws, size_t ws_size,
                              hipStream_t stream) {
  const float* e1 = (const float*)d_in[0];
  const float* e2 = (const float*)d_in[1];
  float* out = (float*)d_out;

  // ws: [zn 4MB][s_sum 32KB][dacc 32KB][pos_val 32KB]
  unsigned short* zn = (unsigned short*)d_ws;
  float* s_sum   = (float*)((char*)d_ws + (size_t)kN * kD * 2);
  float* dacc    = s_sum + kN;
  float* pos_val = dacc + kN;

  hipLaunchKernelGGL(k_normalize, dim3(kN / 4), dim3(256), 0, stream,
                     e1, e2, zn, s_sum);
  hipLaunchKernelGGL(k_pos, dim3(kBH / 4), dim3(256), 0, stream,
                     zn, pos_val, dacc);
  hipLaunchKernelGGL(k_simlse, dim3(64 * kChunks), dim3(256), 0, stream,
                     zn, s_sum);
  hipLaunchKernelGGL(k_final, dim3(1), dim3(1024), 0, stream,
                     s_sum, dacc, pos_val, out);
}

// Round 15
// 57.795 us; speedup vs baseline: 2.5481x; 1.1028x over previous
//
#include <hip/hip_runtime.h>
#include <hip/hip_bf16.h>

// NCE / NT-Xent loss, B=4096, D=256, temp=0.5.
// loss = mean_i( log(sum_{j!=i} exp(sim_ij)) - sim_{i,(i+B)%N} ), N=8192.
// |sim| <= 2 => exp(sim) <= e^2: plain sum(exp), no online max.
//
// R15: B through LDS with T4 counted-vmcnt deep prefetch.
//   Diagnosis: R14's B-stream = 4MB/CU through the 64B/clk L1 return path
//   (~27us floor, paid per load instruction regardless of hit rate). LDS is
//   the only bypass. R8's LDS attempt failed on 1-deep prefetch + serial
//   barriers; this version stages 3 tiles ahead with vmcnt(6) (never 0),
//   4 rotating 8KB buffers, 2 barriers/tile, branch-free epilogue.
// Algebraic offload (R14): diag stays in row sums, k_final subtracts
//   exp2(||zhat||^2 scaled); pos computed by k_pos as row-pair dots.
//
// Zn stored scaled by sqrt(2*log2(e)) so MFMA output IS the exp2 argument.
// Fragment-tiled Zn: 16-row group g, element (g*16+rr, d), ks=d>>5,
// lhi=(d>>3)&3, dlo=d&7 -> zn[g*4096 + ks*512 + lhi*128 + rr*8 + dlo];
// lane l's fragment ks of group g = 16B at zn + g*4096 + ks*512 + l*8.

constexpr int kN  = 8192;        // 2B rows
constexpr int kD  = 256;         // embedding dim
constexpr int kBH = 4096;        // B
constexpr int kChunks  = 32;     // column chunks (256 cols each)
constexpr int kColsPer = kN / kChunks;
constexpr int kNT = kColsPer / 16;        // 16 tiles per chunk
constexpr float kSqrtScale = 1.6986436f;  // sqrt(2*log2(e))
constexpr float kLn2 = 0.6931471805599453f;

typedef __attribute__((ext_vector_type(8))) short bf16x8;  // 4 VGPRs
typedef __attribute__((ext_vector_type(4))) float f32x4;

__device__ __forceinline__ unsigned short f2bf(float f) {
  union { float f; unsigned u; } x;
  x.f = f;
  unsigned u = x.u;
  return (unsigned short)((u + 0x7FFFu + ((u >> 16) & 1u)) >> 16);
}
__device__ __forceinline__ float bf2f(unsigned short h) {
  union { unsigned u; float f; } x;
  x.u = ((unsigned)h) << 16;
  return x.f;
}
__device__ __forceinline__ void gload_lds16(const short* g, short* l) {
  __builtin_amdgcn_global_load_lds(
      (const __attribute__((address_space(1))) void*)g,
      (__attribute__((address_space(3))) void*)l, 16, 0, 0);
}

// ---------------- kernel 1: row-normalize fp32 -> bf16 (tiled + scaled) ---
// Blocks 0..7 zero s_sum; stream order guarantees completion before k_simlse.
__global__ void k_normalize(const float* __restrict__ e1,
                            const float* __restrict__ e2,
                            unsigned short* __restrict__ zn,
                            float* __restrict__ s_sum) {
  if (blockIdx.x < 8) {
    float4 z4 = {0.f, 0.f, 0.f, 0.f};
    *reinterpret_cast<float4*>(s_sum + blockIdx.x * 1024 + threadIdx.x * 4) = z4;
  }
  const int wave = threadIdx.x >> 6;
  const int lane = threadIdx.x & 63;
  const int row  = blockIdx.x * 4 + wave;
  const float* src = (row < kBH) ? (e1 + (size_t)row * kD)
                                 : (e2 + (size_t)(row - kBH) * kD);
  float4 v = *reinterpret_cast<const float4*>(src + lane * 4);
  float ssq = v.x * v.x + v.y * v.y + v.z * v.z + v.w * v.w;
#pragma unroll
  for (int m = 1; m < 64; m <<= 1) ssq += __shfl_xor(ssq, m);
  const float invs = kSqrtScale / sqrtf(ssq);   // eps can never bind (|z|~16)
  ushort4 o;
  o.x = f2bf(v.x * invs);
  o.y = f2bf(v.y * invs);
  o.z = f2bf(v.z * invs);
  o.w = f2bf(v.w * invs);
  const int g  = row >> 4;
  const int rr = row & 15;
  const size_t dst = (size_t)g * 4096 + (lane >> 3) * 512 +
                     ((lane >> 1) & 3) * 128 + rr * 8 + (lane & 1) * 4;
  *reinterpret_cast<ushort4*>(zn + dst) = o;
}

// ---------------- kernel 1b: row-pair dots (pos + diag), 1 wave/pair ------
__global__ void k_pos(const unsigned short* __restrict__ zn,
                      float* __restrict__ pos_val,
                      float* __restrict__ dacc) {
  const int wave = threadIdx.x >> 6;
  const int lane = threadIdx.x & 63;
  const int i = blockIdx.x * 4 + wave;        // 0..4095
  const int j = i + kBH;
  const int rr = i & 15;
  const size_t off = (size_t)(i >> 4) * 4096 + (lane >> 3) * 512 +
                     ((lane >> 1) & 3) * 128 + rr * 8 + (lane & 1) * 4;
  ushort4 ua = *reinterpret_cast<const ushort4*>(zn + off);
  ushort4 ub = *reinterpret_cast<const ushort4*>(zn + off + (size_t)256 * 4096);
  float dij = 0.f, dii = 0.f, djj = 0.f;
  const unsigned short* pa = &ua.x;
  const unsigned short* pb = &ub.x;
#pragma unroll
  for (int q = 0; q < 4; ++q) {
    const float a = bf2f(pa[q]);
    const float b = bf2f(pb[q]);
    dij += a * b;
    dii += a * a;
    djj += b * b;
  }
#pragma unroll
  for (int m = 1; m < 64; m <<= 1) {
    dij += __shfl_xor(dij, m);
    dii += __shfl_xor(dii, m);
    djj += __shfl_xor(djj, m);
  }
  if (lane == 0) {
    const float p = dij * kLn2;   // scaled-dot * ln2 == sim/temp
    pos_val[i] = p;
    pos_val[j] = p;
    dacc[i] = dii;
    dacc[j] = djj;
  }
}

// ---------------- kernel 2: GEMM + exp + row-sum, LDS-B pipeline ----------
// Grid: 64 row-tiles (128 rows) x 32 col-chunks (256 cols) = 2048 blocks.
// Block: 4 waves x 32 rows. Per tile (16 cols x 256d = 8KB, shared by all
// 4 waves from LDS): barrier; stage(t+3); vmcnt(6); barrier; read+MFMA+exp.
__global__ __launch_bounds__(256, 4)
void k_simlse(const unsigned short* __restrict__ zn,
              float* __restrict__ s_sum) {
  __shared__ __align__(16) short ldsB[4][4096];   // 4 rotating 8KB tiles

  const int bid = blockIdx.x;
  const int rt  = bid >> 5;   // row tile 0..63
  const int ch  = bid & 31;   // column chunk 0..31 (fast -> XCD L2 spread)
  const int wave = threadIdx.x >> 6;
  const int lane = threadIdx.x & 63;
  const int l15 = lane & 15;
  const int lhi = lane >> 4;
  const int rowBase = rt * 128 + wave * 32;
  const int grpBase = ch * kNT;   // first 16-col group of this chunk

  // ---- A fragments (2 groups = 32 rows) ----
  bf16x8 a0[8], a1[8];
  {
    const unsigned short* ap = zn + (size_t)(rowBase >> 4) * 4096 + lane * 8;
#pragma unroll
    for (int ks = 0; ks < 8; ++ks) {
      a0[ks] = *reinterpret_cast<const bf16x8*>(ap + ks * 512);
      a1[ks] = *reinterpret_cast<const bf16x8*>(ap + 4096 + ks * 512);
    }
  }

  // Stage tile (t&15) into buffer (t&3); each wave copies its 2KB slice.
  auto stage = [&](int t) {
    const short* src = (const short*)zn +
                       (size_t)(grpBase + (t & (kNT - 1))) * 4096 + wave * 1024;
    short* dst = &ldsB[t & 3][wave * 1024];
    gload_lds16(src + lane * 8, dst);
    gload_lds16(src + 512 + lane * 8, dst + 512);
  };

  stage(0);
  stage(1);
  stage(2);
  // Drain A-loads AND prologue stages: makes in-loop vmcnt counting exact
  // (immune to compiler reordering of the prologue loads).
  asm volatile("s_waitcnt vmcnt(0)" ::: "memory");

  float sacc[2][4] = {{0.f,0.f,0.f,0.f},{0.f,0.f,0.f,0.f}};

#pragma unroll 1
  for (int t = 0; t < kNT; ++t) {
    __builtin_amdgcn_s_barrier();   // A: all waves done reading tile t-1
    stage(t + 3);                   // overwrites tile t-1's buffer (safe)
    asm volatile("s_waitcnt vmcnt(6)" ::: "memory");  // tile t's loads done
    __builtin_amdgcn_s_barrier();   // B: tile t fully resident for all waves

    const short* bt = &ldsB[t & 3][0];
    bf16x8 b[8];
#pragma unroll
    for (int ks = 0; ks < 8; ++ks)
      b[ks] = *reinterpret_cast<const bf16x8*>(bt + ks * 512 + lane * 8);

    f32x4 acc0 = {0.f,0.f,0.f,0.f};
    f32x4 acc1 = {0.f,0.f,0.f,0.f};
#pragma unroll
    for (int ks = 0; ks < 8; ++ks) {
      acc0 = __builtin_amdgcn_mfma_f32_16x16x32_bf16(a0[ks], b[ks], acc0, 0, 0, 0);
      acc1 = __builtin_amdgcn_mfma_f32_16x16x32_bf16(a1[ks], b[ks], acc1, 0, 0, 0);
    }
    // branch-free epilogue: 8 exp2 + 8 add (diag/pos handled elsewhere)
#pragma unroll
    for (int j = 0; j < 4; ++j) {
      sacc[0][j] += exp2f(acc0[j]);
      sacc[1][j] += exp2f(acc1[j]);
    }
  }

  // ---- fold across the 16-lane column group; l15==0 lanes own rows ----
#pragma unroll
  for (int s = 0; s < 2; ++s) {
#pragma unroll
    for (int j = 0; j < 4; ++j) {
      float sv = sacc[s][j];
#pragma unroll
      for (int m = 1; m < 16; m <<= 1) sv += __shfl_xor(sv, m);
      if (l15 == 0) {
        const int row = rowBase + s * 16 + lhi * 4 + j;
        atomicAdd(&s_sum[row], sv);
      }
    }
  }
}

// ---------------- kernel 3: log(S - diag) - pos, final reduce -------------
__global__ void k_final(const float* __restrict__ s_sum,
                        const float* __restrict__ dacc,
                        const float* __restrict__ pos_val,
                        float* __restrict__ out) {
  __shared__ float red[16];
  float acc = 0.0f;
  for (int r = threadIdx.x; r < kN; r += 1024)
    acc += logf(s_sum[r] - exp2f(dacc[r])) - pos_val[r];
#pragma unroll
  for (int m = 1; m < 64; m <<= 1) acc += __shfl_xor(acc, m);
  const int wave = threadIdx.x >> 6;
  const int lane = threadIdx.x & 63;
  if (lane == 0) red[wave] = acc;
  __syncthreads();
  if (threadIdx.x == 0) {
    float t = 0.0f;
#pragma unroll
    for (int w = 0; w < 16; ++w) t += red[w];
    out[0] = t / (float)kN;
  }
}

extern "C" void kernel_launch(void* const* d_in, const int* in_sizes, int n_in,
                              void* d_out, int out_size, void* d_ws, size_t ws_size,
                              hipStream_t stream) {
  const float* e1 = (const float*)d_in[0];
  const float* e2 = (const float*)d_in[1];
  float* out = (float*)d_out;

  // ws: [zn 4MB][s_sum 32KB][dacc 32KB][pos_val 32KB]
  unsigned short* zn = (unsigned short*)d_ws;
  float* s_sum   = (float*)((char*)d_ws + (size_t)kN * kD * 2);
  float* dacc    = s_sum + kN;
  float* pos_val = dacc + kN;

  hipLaunchKernelGGL(k_normalize, dim3(kN / 4), dim3(256), 0, stream,
                     e1, e2, zn, s_sum);
  hipLaunchKernelGGL(k_pos, dim3(kBH / 4), dim3(256), 0, stream,
                     zn, pos_val, dacc);
  hipLaunchKernelGGL(k_simlse, dim3(64 * kChunks), dim3(256), 0, stream,
                     zn, s_sum);
  hipLaunchKernelGGL(k_final, dim3(1), dim3(1024), 0, stream,
                     s_sum, dacc, pos_val, out);
}